// Round 7
// baseline (106.163 us; speedup 1.0000x reference)
//
#include <hip/hip_runtime.h>
#include <stdint.h>

// VQ codebook assignment via split-precision bf16 MFMA:
//   argmin_k ||z-c_k||^2 == argmin_k (csq[k] - 2 z.c_k)
//   z.c ~= z_hi.c_hi + z_lo.c_hi + z_hi.c_lo   (bf16 hi/lo split, K_eff=768)
// Round-7: 32x32x16 MFMA, 1024-thr block (16 waves), wave owns 64 codes x
// 64 q -> whole codebook in ONE pass, z-tile read ONCE per wave (LDS-pipe
// 2 MB/CU << MFMA 49.6K cyc). acc = 4 x f32x16 = 64 regs; launch_bounds
// (1024,4) keeps 16 waves resident. No barriers in main loop. fp64 fixup.

#define NQ 32768
#define ND 256
#define NK 1024
#define TAU 0.0078125f   // 2^-7 margin threshold for the exact-fixup path

typedef short bf16x8  __attribute__((ext_vector_type(8)));
typedef float f32x16  __attribute__((ext_vector_type(16)));

// ws layout (bytes); total ~1.19 MB
// cbw: ushort [64 koct][1024 codes][8]; koct 0..31 = c_hi octet, 32..63 = c_lo
#define WS_CBW 0
#define WS_CSQ (64 * 1024 * 8 * 2)       // 1 MB; then double csq[1024]
#define WS_CNT (WS_CSQ + 1024 * 8)
#define WS_LST (WS_CNT + 16)
#define WS_NEEDED (WS_LST + NQ * 4)

__device__ __forceinline__ ushort bf_trunc(float x) {
    return (ushort)(__builtin_bit_cast(uint32_t, x) >> 16);
}
__device__ __forceinline__ float bf_back(ushort h) {
    return __builtin_bit_cast(float, ((uint32_t)h) << 16);
}

// ---------------------------------------------------------------- prep ----
// 256 blocks x 256 threads; each wave converts one code row (4 codes/block).
__global__ __launch_bounds__(256)
void vq_prep(const float* __restrict__ cb, uint8_t* __restrict__ ws)
{
    ushort* cbw = (ushort*)(ws + WS_CBW);
    double* csq = (double*)(ws + WS_CSQ);
    int*    cnt = (int*)(ws + WS_CNT);

    const int tid  = threadIdx.x;
    const int code = blockIdx.x * 4 + (tid >> 6);
    const int lane = tid & 63;
    if (blockIdx.x == 0 && tid == 0) *cnt = 0;   // re-zero (determinism)

    const int d0 = lane * 4;
    const float4 v = *reinterpret_cast<const float4*>(&cb[(size_t)code * ND + d0]);
    const float xs[4] = {v.x, v.y, v.z, v.w};

    ushort4 h4, l4;
    ushort* hp = &h4.x; ushort* lp = &l4.x;
    double ss = 0.0;
    #pragma unroll
    for (int j = 0; j < 4; ++j) {
        const ushort h = bf_trunc(xs[j]);
        hp[j] = h;
        lp[j] = bf_trunc(xs[j] - bf_back(h));
        ss += (double)xs[j] * (double)xs[j];
    }

    const int oct = d0 >> 3;             // 0..31
    const int off = d0 & 7;              // 0 or 4
    *reinterpret_cast<ushort4*>(&cbw[((size_t)oct * NK + code) * 8 + off]) = h4;
    *reinterpret_cast<ushort4*>(&cbw[((size_t)(32 + oct) * NK + code) * 8 + off]) = l4;

    #pragma unroll
    for (int m = 1; m < 64; m <<= 1) ss += __shfl_xor(ss, m);
    if (lane == 0) csq[code] = ss;
}

// ---------------------------------------------------------------- main ----
// 1024 threads = 16 waves; block = 64 queries x 1024 codes, single pass.
// Wave owns 64 codes (2 ct sub-tiles of 32) x 64 q (2 qt sub-tiles of 32).
__global__ __launch_bounds__(1024, 4)
void vq_main(const float* __restrict__ z, const float* __restrict__ cb,
             uint8_t* __restrict__ ws, float* __restrict__ out)
{
    __shared__ ushort zt[64][512];        // z hi(units 0..31)|lo(32..63), XOR-swizzled
    __shared__ float  csq_l[NK];
    __shared__ float  wb1[16][64], wb2[16][64];
    __shared__ int    wbi[16][64];
    __shared__ int    qidx[64];

    const ushort* cbw  = (const ushort*)(ws + WS_CBW);
    const double* csqd = (const double*)(ws + WS_CSQ);
    int* cnt = (int*)(ws + WS_CNT);
    int* lst = (int*)(ws + WS_LST);

    const int tid  = threadIdx.x;
    const int lane = tid & 63;
    const int w    = tid >> 6;            // wave 0..15 -> 64-code stripe
    const int c32  = lane & 31;
    const int hh   = lane >> 5;           // 0/1: k-octet half & code-row offset
    const int q0   = blockIdx.x * 64;
    const int cbase = w * 64;

    // --- stage z tile: 64q x 256d fp32 -> hi/lo bf16, swizzled 16B units
    {
        const int rr = tid >> 6;          // 0..15
        const int c4 = (tid & 63) * 4;
        const int uh = c4 >> 3;           // hi unit 0..31
        const int ul = (256 + c4) >> 3;   // lo unit 32..63
        #pragma unroll
        for (int it = 0; it < 4; ++it) {
            const int q = it * 16 + rr;
            const float4 v = *reinterpret_cast<const float4*>(
                &z[(size_t)(q0 + q) * ND + c4]);
            const float xs[4] = {v.x, v.y, v.z, v.w};
            ushort4 h4, l4;
            ushort* hp = &h4.x; ushort* lp = &l4.x;
            #pragma unroll
            for (int j = 0; j < 4; ++j) {
                const ushort h = bf_trunc(xs[j]);
                hp[j] = h;
                lp[j] = bf_trunc(xs[j] - bf_back(h));
            }
            const int sw = q & 7;
            *reinterpret_cast<ushort4*>(&zt[q][((uh ^ sw) << 3) + (c4 & 7)]) = h4;
            *reinterpret_cast<ushort4*>(&zt[q][((ul ^ sw) << 3) + (c4 & 7)]) = l4;
        }
    }
    csq_l[tid] = (float)csqd[tid];
    __syncthreads();

    f32x16 acc[2][2];                     // [ct][qt], static indices only
    #pragma unroll
    for (int ct = 0; ct < 2; ++ct)
        #pragma unroll
        for (int qt = 0; qt < 2; ++qt)
            acc[ct][qt] = (f32x16)(0.f);

    // --- main loop: 16 steps of 16 d; A from L2, z from LDS (once)
    #pragma unroll 4
    for (int s = 0; s < 16; ++s) {
        const int oh = 2 * s + hh;        // hi k-octet index for this lane
        bf16x8 cfh[2], cfl[2];
        #pragma unroll
        for (int ct = 0; ct < 2; ++ct) {
            const int code = cbase + ct * 32 + c32;
            cfh[ct] = *reinterpret_cast<const bf16x8*>(
                &cbw[((size_t)oh * NK + code) * 8]);
            cfl[ct] = *reinterpret_cast<const bf16x8*>(
                &cbw[((size_t)(32 + oh) * NK + code) * 8]);
        }
        bf16x8 zfh[2], zfl[2];
        #pragma unroll
        for (int qt = 0; qt < 2; ++qt) {
            const int q  = qt * 32 + c32;
            const int uh = oh ^ (q & 7);
            const int ul = (32 + oh) ^ (q & 7);
            zfh[qt] = *reinterpret_cast<const bf16x8*>(&zt[q][uh << 3]);
            zfl[qt] = *reinterpret_cast<const bf16x8*>(&zt[q][ul << 3]);
        }
        #pragma unroll
        for (int ct = 0; ct < 2; ++ct)
            #pragma unroll
            for (int qt = 0; qt < 2; ++qt) {
                acc[ct][qt] = __builtin_amdgcn_mfma_f32_32x32x16_bf16(
                    cfh[ct], zfh[qt], acc[ct][qt], 0, 0, 0);
                acc[ct][qt] = __builtin_amdgcn_mfma_f32_32x32x16_bf16(
                    cfh[ct], zfl[qt], acc[ct][qt], 0, 0, 0);
                acc[ct][qt] = __builtin_amdgcn_mfma_f32_32x32x16_bf16(
                    cfl[ct], zfh[qt], acc[ct][qt], 0, 0, 0);
            }
    }

    // --- fold into per-lane top-2 (one q per qt-tile per lane)
    // D mapping: col=lane&31 -> q, row=(reg&3)+8*(reg>>2)+4*(lane>>5) -> code
    float b1[2], b2[2]; int bidx[2];
    #pragma unroll
    for (int qt = 0; qt < 2; ++qt) { b1[qt] = 3.0e38f; b2[qt] = 3.0e38f; bidx[qt] = 0; }

    #pragma unroll
    for (int ct = 0; ct < 2; ++ct) {
        const int base = cbase + ct * 32 + 4 * hh;
        #pragma unroll
        for (int rq = 0; rq < 4; ++rq) {
            const int kb = base + 8 * rq;
            const float4 cs4 = *reinterpret_cast<const float4*>(&csq_l[kb]);
            const float css[4] = {cs4.x, cs4.y, cs4.z, cs4.w};
            #pragma unroll
            for (int r0 = 0; r0 < 4; ++r0) {
                const int r = rq * 4 + r0;
                #pragma unroll
                for (int qt = 0; qt < 2; ++qt) {
                    const float d = fmaf(-2.0f, acc[ct][qt][r], css[r0]);
                    if (d < b1[qt]) { b2[qt] = b1[qt]; b1[qt] = d; bidx[qt] = kb + r0; }
                    else if (d < b2[qt]) b2[qt] = d;
                }
            }
        }
    }

    // --- merge lane <-> lane^32 (same q, complementary code rows)
    #pragma unroll
    for (int qt = 0; qt < 2; ++qt) {
        const float o1 = __shfl_xor(b1[qt], 32);
        const float o2 = __shfl_xor(b2[qt], 32);
        const int   oi = __shfl_xor(bidx[qt], 32);
        const float n2 = fminf(fmaxf(b1[qt], o1), fminf(b2[qt], o2));
        const bool sel = (o1 < b1[qt]) || (o1 == b1[qt] && oi < bidx[qt]);
        b1[qt] = fminf(b1[qt], o1);
        bidx[qt] = sel ? oi : bidx[qt];
        b2[qt] = n2;
        if (lane < 32) {
            wb1[w][qt * 32 + c32] = b1[qt];
            wb2[w][qt * 32 + c32] = b2[qt];
            wbi[w][qt * 32 + c32] = bidx[qt];
        }
    }
    __syncthreads();

    // --- combine 16 wave candidates, flag tight margins
    if (tid < 64) {
        float B1 = wb1[0][tid], B2 = wb2[0][tid]; int BI = wbi[0][tid];
        #pragma unroll
        for (int ww = 1; ww < 16; ++ww) {
            const float o1 = wb1[ww][tid], o2 = wb2[ww][tid];
            const int   oi = wbi[ww][tid];
            const float n2 = fminf(fmaxf(B1, o1), fminf(B2, o2));
            const bool sel = (o1 < B1) || (o1 == B1 && oi < BI);
            B1 = fminf(B1, o1); BI = sel ? oi : BI; B2 = n2;
        }
        qidx[tid] = BI;
        if (B2 - B1 < TAU) {
            const int pos = atomicAdd(cnt, 1);
            lst[pos] = q0 + tid;
        }
    }
    __syncthreads();

    // --- gather: out[q][:] = cb[idx[q]][:]
    {
        const int rr = tid >> 6;
        const int c  = (tid & 63) * 4;
        #pragma unroll
        for (int it = 0; it < 4; ++it) {
            const int q = it * 16 + rr;
            const int k = qidx[q];
            *reinterpret_cast<float4*>(&out[(size_t)(q0 + q) * ND + c]) =
                *reinterpret_cast<const float4*>(&cb[(size_t)k * ND + c]);
        }
    }
}

// --------------------------------------------------------------- fixup ----
// Exact fp64 re-solve for flagged (tight-margin) queries.
__global__ __launch_bounds__(256, 1)
void vq_fix(const float* __restrict__ z, const float* __restrict__ cb,
            uint8_t* __restrict__ ws, float* __restrict__ out)
{
    __shared__ double zd[ND];
    __shared__ double rb[256];
    __shared__ int    ri[256];

    const int* cnt = (const int*)(ws + WS_CNT);
    const int* lst = (const int*)(ws + WS_LST);
    const int tid = threadIdx.x;
    const int n = *cnt;

    for (int i = blockIdx.x; i < n; i += gridDim.x) {
        const int q = lst[i];
        __syncthreads();
        zd[tid] = (double)z[(size_t)q * ND + tid];
        __syncthreads();

        double best = 1.0e300; int bi = 0;
        #pragma unroll 1
        for (int j = 0; j < 4; ++j) {
            const int k = tid * 4 + j;
            double s = 0.0;
            const float* row = &cb[(size_t)k * ND];
            for (int d = 0; d < ND; ++d) {
                const double df = zd[d] - (double)row[d];
                s = fma(df, df, s);
            }
            if (s < best) { best = s; bi = k; }
        }
        rb[tid] = best; ri[tid] = bi;
        __syncthreads();
        for (int m = 128; m > 0; m >>= 1) {
            if (tid < m) {
                if (rb[tid + m] < rb[tid] ||
                    (rb[tid + m] == rb[tid] && ri[tid + m] < ri[tid])) {
                    rb[tid] = rb[tid + m]; ri[tid] = ri[tid + m];
                }
            }
            __syncthreads();
        }
        const int k = ri[0];
        if (tid < 64) {
            const float4 vv = *reinterpret_cast<const float4*>(
                &cb[(size_t)k * ND + tid * 4]);
            *reinterpret_cast<float4*>(&out[(size_t)q * ND + tid * 4]) = vv;
        }
        __syncthreads();
    }
}

// ------------------------------------------------- fallback (round-1) -----
// Verified-passing fp32 VALU kernel, used only if ws_size is insufficient.
__global__ __launch_bounds__(256, 2)
void vq_fallback(const float* __restrict__ z, const float* __restrict__ cb,
                 float* __restrict__ out)
{
    __shared__ float z_t[ND][64];
    __shared__ float cb_t[32][64];
    __shared__ float csq[NK];
    __shared__ int   idx_lds[64];

    const int tid = threadIdx.x;
    const int tx  = tid & 15;
    const int ty  = tid >> 4;
    const int q0  = blockIdx.x * 64;

    {
        const int r  = tid >> 6;
        const int c4 = (tid & 63) * 4;
        #pragma unroll
        for (int it = 0; it < 16; ++it) {
            const int q = it * 4 + r;
            const float4 v = *reinterpret_cast<const float4*>(
                &z[(size_t)(q0 + q) * ND + c4]);
            const float vv[4] = {v.x, v.y, v.z, v.w};
            #pragma unroll
            for (int j = 0; j < 4; ++j) {
                const int d = c4 + j;
                const int s = 4 * ((d >> 2) & 7);
                z_t[d][q ^ s] = vv[j];
            }
        }
    }
    {
        const int lane16 = tid & 15;
        const int rgrp   = tid >> 4;
        #pragma unroll 4
        for (int it = 0; it < 64; ++it) {
            const int k = it * 16 + rgrp;
            double ssum = 0.0;
            #pragma unroll
            for (int h = 0; h < 4; ++h) {
                const float4 v = *reinterpret_cast<const float4*>(
                    &cb[(size_t)k * ND + lane16 * 16 + h * 4]);
                ssum += (double)v.x * v.x + (double)v.y * v.y
                      + (double)v.z * v.z + (double)v.w * v.w;
            }
            #pragma unroll
            for (int m = 8; m >= 1; m >>= 1) ssum += __shfl_xor(ssum, m);
            if (lane16 == 0) csq[k] = (float)ssum;
        }
    }

    double bestd[4]; int besti[4];
    #pragma unroll
    for (int i = 0; i < 4; ++i) { bestd[i] = 1e300; besti[i] = 0; }

    for (int kt = 0; kt < 16; ++kt) {
        double acc[4][4];
        #pragma unroll
        for (int i = 0; i < 4; ++i)
            #pragma unroll
            for (int j = 0; j < 4; ++j) acc[i][j] = 0.0;

        for (int dc = 0; dc < 8; ++dc) {
            __syncthreads();
            {
                const int kk = tid >> 3;
                const int dd = (tid & 7) * 4;
                #pragma unroll
                for (int h = 0; h < 2; ++h) {
                    const int k = kk + h * 32;
                    const float4 v = *reinterpret_cast<const float4*>(
                        &cb[(size_t)(kt * 64 + k) * ND + dc * 32 + dd]);
                    const float vv[4] = {v.x, v.y, v.z, v.w};
                    #pragma unroll
                    for (int j = 0; j < 4; ++j) {
                        const int d = dd + j;
                        const int s = 4 * ((d >> 2) & 7);
                        cb_t[d][k ^ s] = vv[j];
                    }
                }
            }
            __syncthreads();

            float cr[4][4];
            #pragma unroll
            for (int i = 0; i < 4; ++i)
                #pragma unroll
                for (int j = 0; j < 4; ++j) cr[i][j] = 0.0f;

            #pragma unroll 8
            for (int d = 0; d < 32; ++d) {
                const int s  = 4 * ((d >> 2) & 7);
                const int dg = dc * 32 + d;
                const float4 zv4 = *reinterpret_cast<const float4*>(
                    &z_t[dg][(4 * ty) ^ s]);
                const float4 cv4 = *reinterpret_cast<const float4*>(
                    &cb_t[d][(4 * tx) ^ s]);
                const float zv[4] = {zv4.x, zv4.y, zv4.z, zv4.w};
                const float cv[4] = {cv4.x, cv4.y, cv4.z, cv4.w};
                #pragma unroll
                for (int i = 0; i < 4; ++i)
                    #pragma unroll
                    for (int j = 0; j < 4; ++j)
                        cr[i][j] = fmaf(zv[i], cv[j], cr[i][j]);
            }
            #pragma unroll
            for (int i = 0; i < 4; ++i)
                #pragma unroll
                for (int j = 0; j < 4; ++j)
                    acc[i][j] += (double)cr[i][j];
        }

        #pragma unroll
        for (int j = 0; j < 4; ++j) {
            const int k = kt * 64 + tx * 4 + j;
            const double cs = (double)csq[k];
            #pragma unroll
            for (int i = 0; i < 4; ++i) {
                const double dist = cs - 2.0 * acc[i][j];
                if (dist < bestd[i]) { bestd[i] = dist; besti[i] = k; }
            }
        }
    }

    #pragma unroll
    for (int i = 0; i < 4; ++i) {
        double bd = bestd[i]; int bi = besti[i];
        #pragma unroll
        for (int m = 8; m >= 1; m >>= 1) {
            const double od = __shfl_xor(bd, m);
            const int    oi = __shfl_xor(bi, m);
            if (od < bd || (od == bd && oi < bi)) { bd = od; bi = oi; }
        }
        if (tx == 0) idx_lds[ty * 4 + i] = bi;
    }
    __syncthreads();

    {
        const int r = tid >> 6;
        const int c = (tid & 63) * 4;
        #pragma unroll
        for (int it = 0; it < 16; ++it) {
            const int q = it * 4 + r;
            const int k = idx_lds[q];
            const float4 v = *reinterpret_cast<const float4*>(
                &cb[(size_t)k * ND + c]);
            *reinterpret_cast<float4*>(&out[(size_t)(q0 + q) * ND + c]) = v;
        }
    }
}

extern "C" void kernel_launch(void* const* d_in, const int* in_sizes, int n_in,
                              void* d_out, int out_size, void* d_ws, size_t ws_size,
                              hipStream_t stream)
{
    const float* z   = (const float*)d_in[0];   // [B,T,D] fp32
    const float* cbk = (const float*)d_in[1];   // [K,D]  fp32
    float* out = (float*)d_out;
    uint8_t* ws = (uint8_t*)d_ws;

    if (ws_size < (size_t)WS_NEEDED) {
        vq_fallback<<<NQ / 64, 256, 0, stream>>>(z, cbk, out);
        return;
    }

    vq_prep<<<NK / 4, 256, 0, stream>>>(cbk, ws);
    vq_main<<<NQ / 64, 1024, 0, stream>>>(z, cbk, ws, out);
    vq_fix<<<64, 256, 0, stream>>>(z, cbk, ws, out);
}